// Round 3
// baseline (126.756 us; speedup 1.0000x reference)
//
#include <hip/hip_runtime.h>

// OpenBoundary neighbor list, N=8192, cutoff=5.0, max_neighbours=32.
// Outputs (int32, concatenated): to_idx[8192][32] | cell_indices[8192][32][3]=0 | actual_max (scalar)
//
// R3 structure: R=2 rows/wave, 512-thread blocks, 512 blocks (2/CU, 4 waves/SIMD).
// LDS float4-padded positions (64KB, 2 passes). Steady-state inner iter:
// ~10 VALU + ~6 SALU per 64 pair-tests; compaction machinery inside a
// wave-uniform `if (mask)` branch skipped ~94% of the time. Self-exclusion
// done on the ballot mask (scalar), not per-lane.

constexpr int   N     = 8192;
constexpr int   MAXNB = 32;
constexpr float CUT2  = 25.0f;   // 5.0^2 exactly representable
constexpr int   R     = 2;       // rows per wave
constexpr int   HALF  = 4096;    // j-points staged per pass
constexpr int   BLOCK = 512;     // 8 waves
constexpr int   ROWS_PER_BLOCK = (BLOCK / 64) * R;   // 16

__global__ __launch_bounds__(BLOCK, 4) void neigh_kernel(const float* __restrict__ pos,
                                                         int* __restrict__ out) {
    __shared__ float4 s4[HALF];            // 64 KB padded xyz_

    const int lane = threadIdx.x & 63;
    const int wave = threadIdx.x >> 6;     // 0..7
    const int row0 = blockIdx.x * ROWS_PER_BLOCK + wave * R;

    int* __restrict__ out_idx = out;                               // [N*MAXNB]
    int* __restrict__ cell    = out + N * MAXNB;                   // [N*MAXNB*3] -> zeros
    int* __restrict__ out_max = out + N * MAXNB + N * MAXNB * 3;   // scalar

    // Zero this block's slice of cell_indices (16 rows x 96 ints), coalesced.
    {
        int* c = cell + (size_t)blockIdx.x * ROWS_PER_BLOCK * MAXNB * 3;
        #pragma unroll
        for (int t = threadIdx.x; t < ROWS_PER_BLOCK * MAXNB * 3; t += BLOCK) c[t] = 0;
    }

    // Per-row (wave-uniform) state.
    float xi[R], yi[R], zi[R];
    int schunk[R], base_i[R];
    unsigned long long sbits[R];
    #pragma unroll
    for (int r = 0; r < R; ++r) {
        const int i = row0 + r;
        xi[r] = pos[3 * i + 0];
        yi[r] = pos[3 * i + 1];
        zi[r] = pos[3 * i + 2];
        schunk[r] = i >> 6;                      // chunk containing self
        sbits[r]  = ~(1ull << (i & 63));         // clear-self bit mask
        base_i[r] = i * MAXNB;
    }

    int count[R] = {0, 0};

    for (int pass = 0; pass < 2; ++pass) {
        if (pass) __syncthreads();               // done reading previous LDS contents
        // Stage HALF points as padded float4 (reads are L2-resident).
        for (int p = threadIdx.x; p < HALF; p += BLOCK) {
            const int g = pass * HALF + p;
            s4[p] = make_float4(pos[3 * g], pos[3 * g + 1], pos[3 * g + 2], 0.0f);
        }
        __syncthreads();

        const int jbase = pass * HALF;
        float4 cur = s4[lane];                   // register double-buffer
        for (int b = 0; b < HALF; b += 64) {
            const int nb = (b + 64 < HALF) ? b + 64 : 0;   // clamped prefetch addr
            const float4 nxt = s4[nb + lane];
            const int cid = (jbase + b) >> 6;
            #pragma unroll
            for (int r = 0; r < R; ++r) {
                // numpy f32 rounding: no FMA contraction, ((dx^2+dy^2)+dz^2)
                const float dx = __fsub_rn(xi[r], cur.x);
                const float dy = __fsub_rn(yi[r], cur.y);
                const float dz = __fsub_rn(zi[r], cur.z);
                const float r2 = __fadd_rn(__fadd_rn(__fmul_rn(dx, dx), __fmul_rn(dy, dy)),
                                           __fmul_rn(dz, dz));
                unsigned long long m = __ballot(r2 <= CUT2);
                if (cid == schunk[r]) m &= sbits[r];       // drop self (uniform)
                if (m) {                                   // uniform, taken ~6%
                    const int pre = __builtin_amdgcn_mbcnt_hi(
                        (unsigned int)(m >> 32),
                        __builtin_amdgcn_mbcnt_lo((unsigned int)m, 0u));
                    const int p = count[r] + pre;
                    if (((m >> lane) & 1ull) && p < MAXNB)
                        out_idx[base_i[r] + p] = jbase + b + lane;
                }
                count[r] += __popcll(m);
            }
            cur = nxt;
        }
    }

    // Fill unused slots with -1 (disjoint from hit-written slots).
    #pragma unroll
    for (int r = 0; r < R; ++r) {
        if (lane >= count[r] && lane < MAXNB) out_idx[base_i[r] + lane] = -1;
    }

    // Scalar: max over rows of the FULL neighbor count (not clamped to 32).
    // Poison/zero in the slot is <= 0, a valid identity for signed atomicMax.
    int mx = count[0];
    #pragma unroll
    for (int r = 1; r < R; ++r) mx = max(mx, count[r]);
    if (lane == 0) atomicMax(out_max, mx);
}

extern "C" void kernel_launch(void* const* d_in, const int* in_sizes, int n_in,
                              void* d_out, int out_size, void* d_ws, size_t ws_size,
                              hipStream_t stream) {
    const float* pos = (const float*)d_in[0];   // [8192, 3] f32
    int* out = (int*)d_out;

    const int grid = N / ROWS_PER_BLOCK;        // 512 blocks = 2/CU
    neigh_kernel<<<grid, BLOCK, 0, stream>>>(pos, out);
}